// Round 1
// baseline (173.245 us; speedup 1.0000x reference)
//
#include <hip/hip_runtime.h>
#include <hip/hip_bf16.h>
#include <math.h>

#define DIM 1024
#define HEADS 16
#define DH 64
#define WINDOW 32
#define TSEQ 2048
#define BB 2
#define ROWS (BB * TSEQ)      // 4096
#define NQKV (3 * DIM)        // 3072

typedef __bf16 bf16x8 __attribute__((ext_vector_type(8)));
typedef float f32x4 __attribute__((ext_vector_type(4)));

__device__ __forceinline__ unsigned short f2bf(float f) {
  unsigned int u = __float_as_uint(f);
  u += 0x7fffu + ((u >> 16) & 1u);   // round-to-nearest-even
  return (unsigned short)(u >> 16);
}

__device__ __forceinline__ void glds16(const void* g, void* l) {
  __builtin_amdgcn_global_load_lds((const __attribute__((address_space(1))) void*)g,
                                   (__attribute__((address_space(3))) void*)l,
                                   16, 0, 0);
}

// ---------------- weight fp32 -> bf16 conversion ----------------
__global__ void cvt_bf16(const float* __restrict__ in, unsigned short* __restrict__ out, int n4) {
  int i = blockIdx.x * blockDim.x + threadIdx.x;
  if (i < n4) {
    float4 v = *(const float4*)&in[(size_t)i * 4];
    ushort4 o = make_ushort4(f2bf(v.x), f2bf(v.y), f2bf(v.z), f2bf(v.w));
    *(ushort4*)&out[(size_t)i * 4] = o;
  }
}

// ---------------- RoPE cos/sin table: [TSEQ][32] ----------------
__global__ void rope_tab(float* __restrict__ ctab, float* __restrict__ stab) {
  int idx = blockIdx.x * blockDim.x + threadIdx.x;  // 2048*32
  int t = idx >> 5, i = idx & 31;
  float inv = powf(10000.0f, -(float)i / 32.0f);
  float f = (float)t * inv;
  float sv, cv;
  sincosf(f, &sv, &cv);
  ctab[idx] = cv;
  stab[idx] = sv;
}

// ---------------- LayerNorm -> bf16 ----------------
__global__ __launch_bounds__(256) void ln_kernel(
    const float* __restrict__ x, const float* __restrict__ lw,
    const float* __restrict__ lb, unsigned short* __restrict__ xn) {
  const int row = blockIdx.x;
  const int c = threadIdx.x * 4;  // DIM/256 = 4 per thread
  const float4 v = *(const float4*)&x[(size_t)row * DIM + c];
  float s = v.x + v.y + v.z + v.w;
  float s2 = v.x * v.x + v.y * v.y + v.z * v.z + v.w * v.w;
#pragma unroll
  for (int m = 32; m; m >>= 1) {
    s += __shfl_xor(s, m);
    s2 += __shfl_xor(s2, m);
  }
  __shared__ float ps[4], ps2[4];
  if ((threadIdx.x & 63) == 0) {
    ps[threadIdx.x >> 6] = s;
    ps2[threadIdx.x >> 6] = s2;
  }
  __syncthreads();
  s = ps[0] + ps[1] + ps[2] + ps[3];
  s2 = ps2[0] + ps2[1] + ps2[2] + ps2[3];
  const float mu = s * (1.0f / DIM);
  const float rs = rsqrtf(s2 * (1.0f / DIM) - mu * mu + 1e-5f);
  const float4 wv = *(const float4*)&lw[c];
  const float4 bv = *(const float4*)&lb[c];
  ushort4 o = make_ushort4(f2bf((v.x - mu) * rs * wv.x + bv.x),
                           f2bf((v.y - mu) * rs * wv.y + bv.y),
                           f2bf((v.z - mu) * rs * wv.z + bv.z),
                           f2bf((v.w - mu) * rs * wv.w + bv.w));
  *(ushort4*)&xn[(size_t)row * DIM + c] = o;
}

// ---------------- bf16 MFMA GEMM: C[M,N] = A[M,K] * B[N,K]^T (+resid) ----------------
// m97 structure: 128x128 tile, BK=32, 4 waves (2x2), 16x16x32 MFMA, global_load_lds w16.
__global__ __launch_bounds__(256) void gemm_bt(
    const unsigned short* __restrict__ A, const unsigned short* __restrict__ B,
    float* __restrict__ C, const float* __restrict__ resid,
    int M, int N, int K) {
  __shared__ unsigned short Al[128 * 32];
  __shared__ unsigned short Bl[128 * 32];
  const int t = threadIdx.x;
  const int lane = t & 63;
  const int wave = t >> 6;
  const int wm = wave >> 1;
  const int wn = wave & 1;
  const int bm = blockIdx.y * 128;
  const int bn = blockIdx.x * 128;

  f32x4 acc[4][4] = {};

  const int srow = t >> 2;          // 0..63: row within 64-row chunk
  const int scol = (t & 3) * 8;     // k element offset (8 bf16 = 16B)
  const unsigned short* ga = A + (size_t)(bm + srow) * K + scol;
  const unsigned short* gb = B + (size_t)(bn + srow) * K + scol;
  unsigned short* la = Al + (t & ~63) * 8;   // wave-uniform LDS base
  unsigned short* lb = Bl + (t & ~63) * 8;

  const int fr = lane & 15;
  const int fko = (lane >> 4) * 8;

  for (int k0 = 0; k0 < K; k0 += 32) {
    __syncthreads();  // previous iter's LDS reads done
    glds16(ga + k0, la);
    glds16(ga + (size_t)64 * K + k0, la + 64 * 32);
    glds16(gb + k0, lb);
    glds16(gb + (size_t)64 * K + k0, lb + 64 * 32);
    __syncthreads();  // staging complete (vmcnt(0) before barrier)
    bf16x8 af[4], bfr[4];
#pragma unroll
    for (int i = 0; i < 4; ++i)
      af[i] = *(const bf16x8*)&Al[(wm * 64 + i * 16 + fr) * 32 + fko];
#pragma unroll
    for (int j = 0; j < 4; ++j)
      bfr[j] = *(const bf16x8*)&Bl[(wn * 64 + j * 16 + fr) * 32 + fko];
#pragma unroll
    for (int i = 0; i < 4; ++i)
#pragma unroll
      for (int j = 0; j < 4; ++j)
        acc[i][j] = __builtin_amdgcn_mfma_f32_16x16x32_bf16(af[i], bfr[j], acc[i][j], 0, 0, 0);
  }

  const int cr = (lane >> 4) * 4;
  const int cc = lane & 15;
#pragma unroll
  for (int i = 0; i < 4; ++i)
#pragma unroll
    for (int j = 0; j < 4; ++j)
#pragma unroll
      for (int r = 0; r < 4; ++r) {
        int row = bm + wm * 64 + i * 16 + cr + r;
        int col = bn + wn * 64 + j * 16 + cc;
        size_t idx = (size_t)row * N + col;
        float v = acc[i][j][r];
        if (resid) v += resid[idx];
        C[idx] = v;
      }
}

// ---------------- RoPE apply (in-place on qkv), folds 1/8 scale into q ----------------
__global__ void rope_apply(float* __restrict__ qkv, const float* __restrict__ ctab,
                           const float* __restrict__ stab) {
  int idx = blockIdx.x * blockDim.x + threadIdx.x;  // ROWS*HEADS*32
  int row = idx >> 9;
  int rem = idx & 511;
  int h = rem >> 5, i = rem & 31;
  int pos = row & (TSEQ - 1);
  float cv = ctab[pos * 32 + i];
  float sv = stab[pos * 32 + i];
  float* q = qkv + (size_t)row * NQKV + h * 64 + i;
  float q1 = q[0], q2 = q[32];
  q[0]  = (q1 * cv - q2 * sv) * 0.125f;
  q[32] = (q2 * cv + q1 * sv) * 0.125f;
  float* k = q + DIM;
  float k1 = k[0], k2 = k[32];
  k[0]  = k1 * cv - k2 * sv;
  k[32] = k2 * cv + k1 * sv;
}

// ---------------- sliding-window attention ----------------
// grid (T/64, B*H); block 256 (4 waves). Each block: 64 queries of one (b,h).
// LDS: K rows [qstart-31 .. qstart+63] (95), V same, Q 64 rows.
__global__ __launch_bounds__(256) void attn_kernel(const float* __restrict__ qkv,
                                                   unsigned short* __restrict__ out) {
  __shared__ float Kl[95 * 65];   // stride 65: conflict-free lane-strided reads
  __shared__ float Vl[95 * 64];   // stride 64: consecutive-lane reads, 2-way (free)
  __shared__ float Ql[64 * 64];   // broadcast reads
  const int qtile = blockIdx.x;
  const int bh = blockIdx.y;
  const int b = bh >> 4, h = bh & 15;
  const int qstart = qtile * 64;
  const int t = threadIdx.x;

  for (int e = t; e < 95 * 64; e += 256) {
    int r = e >> 6, d = e & 63;
    int j = qstart - 31 + r;
    float kv = 0.f, vv = 0.f;
    if (j >= 0) {
      size_t base = ((size_t)(b * TSEQ + j)) * NQKV + h * 64 + d;
      kv = qkv[base + DIM];
      vv = qkv[base + 2 * DIM];
    }
    Kl[r * 65 + d] = kv;
    Vl[r * 64 + d] = vv;
  }
  for (int e = t; e < 64 * 64; e += 256) {
    int r = e >> 6, d = e & 63;
    Ql[r * 64 + d] = qkv[((size_t)(b * TSEQ + qstart + r)) * NQKV + h * 64 + d];
  }
  __syncthreads();

  const int wave = t >> 6;
  const int lane = t & 63;
  const int half = lane >> 5;
  const int l = lane & 31;

  for (int qi = 0; qi < 8; ++qi) {
    const int q0 = wave * 16 + qi * 2;
    const int q = q0 + half;          // this half-wave's local query
    // ---- scores: lane l handles key local row q+l ----
    const float* kr = &Kl[(q + l) * 65];
    const float* qr = &Ql[q * 64];
    float s = 0.f;
#pragma unroll
    for (int d = 0; d < 64; ++d) s += qr[d] * kr[d];
    bool valid = (qstart + q + l - 31) >= 0;
    s = valid ? s : -1e30f;
    // ---- softmax across the 32 lanes of this half ----
    float m = s;
#pragma unroll
    for (int mm = 16; mm; mm >>= 1) m = fmaxf(m, __shfl_xor(m, mm));
    float p = __expf(s - m);
    float sum = p;
#pragma unroll
    for (int mm = 16; mm; mm >>= 1) sum += __shfl_xor(sum, mm);
    p /= sum;
    // ---- PV: all 64 lanes, lane = output dim d; shuffle-broadcast p ----
    float acc0 = 0.f, acc1 = 0.f;
#pragma unroll
    for (int kk = 0; kk < 32; ++kk) {
      float p0 = __shfl(p, kk);
      float p1 = __shfl(p, kk + 32);
      acc0 += p0 * Vl[(q0 + kk) * 64 + lane];
      acc1 += p1 * Vl[(q0 + 1 + kk) * 64 + lane];
    }
    size_t ob = ((size_t)(b * TSEQ + qstart + q0)) * DIM + h * 64 + lane;
    out[ob] = f2bf(acc0);
    out[ob + DIM] = f2bf(acc1);
  }
}

extern "C" void kernel_launch(void* const* d_in, const int* in_sizes, int n_in,
                              void* d_out, int out_size, void* d_ws, size_t ws_size,
                              hipStream_t stream) {
  const float* x    = (const float*)d_in[0];
  const float* lw   = (const float*)d_in[1];
  const float* lbp  = (const float*)d_in[2];
  const float* wqkv = (const float*)d_in[3];
  const float* wout = (const float*)d_in[4];
  float* out = (float*)d_out;

  char* w = (char*)d_ws;
  unsigned short* xn  = (unsigned short*)(w);              //  8 MiB: [4096][1024] bf16
  unsigned short* wqb = (unsigned short*)(w + 8388608);    //  6 MiB: [3072][1024] bf16
  unsigned short* wob = (unsigned short*)(w + 14680064);   //  2 MiB: [1024][1024] bf16
  unsigned short* atb = (unsigned short*)(w + 16777216);   //  8 MiB: [4096][1024] bf16
  float* ctab = (float*)(w + 25165824);                    // 256 KiB
  float* stab = (float*)(w + 25427968);                    // 256 KiB
  float* qkv  = (float*)(w + 25690112);                    // 48 MiB: [4096][3072] f32

  cvt_bf16<<<3072, 256, 0, stream>>>(wqkv, wqb, 786432);
  cvt_bf16<<<1024, 256, 0, stream>>>(wout, wob, 262144);
  rope_tab<<<256, 256, 0, stream>>>(ctab, stab);
  ln_kernel<<<ROWS, 256, 0, stream>>>(x, lw, lbp, xn);
  gemm_bt<<<dim3(24, 32), 256, 0, stream>>>(xn, wqb, qkv, nullptr, ROWS, NQKV, DIM);
  rope_apply<<<8192, 256, 0, stream>>>(qkv, ctab, stab);
  attn_kernel<<<dim3(32, 32), 256, 0, stream>>>(qkv, atb);
  gemm_bt<<<dim3(8, 32), 256, 0, stream>>>(atb, wob, out, x, ROWS, DIM, DIM);
}

// Round 3
// 101.092 us; speedup vs baseline: 1.7137x; 1.7137x over previous
//
#include <hip/hip_runtime.h>
#include <hip/hip_bf16.h>
#include <math.h>

#define DIM 1024
#define HEADS 16
#define DH 64
#define WINDOW 32
#define TSEQ 2048
#define BB 2
#define ROWS (BB * TSEQ)      // 4096
#define NQKV (3 * DIM)        // 3072

typedef __bf16 bf16x8 __attribute__((ext_vector_type(8)));
typedef unsigned short u16x8 __attribute__((ext_vector_type(8)));
typedef float f32x4 __attribute__((ext_vector_type(4)));

__device__ __forceinline__ unsigned short f2bf(float f) {
  unsigned int u = __float_as_uint(f);
  u += 0x7fffu + ((u >> 16) & 1u);   // round-to-nearest-even
  return (unsigned short)(u >> 16);
}

__device__ __forceinline__ void glds16(const void* g, void* l) {
  __builtin_amdgcn_global_load_lds((const __attribute__((address_space(1))) void*)g,
                                   (__attribute__((address_space(3))) void*)l,
                                   16, 0, 0);
}

// ---------------- weight fp32 -> bf16 conversion ----------------
__global__ void cvt_bf16(const float* __restrict__ in, unsigned short* __restrict__ out, int n4) {
  int i = blockIdx.x * blockDim.x + threadIdx.x;
  if (i < n4) {
    float4 v = *(const float4*)&in[(size_t)i * 4];
    ushort4 o = make_ushort4(f2bf(v.x), f2bf(v.y), f2bf(v.z), f2bf(v.w));
    *(ushort4*)&out[(size_t)i * 4] = o;
  }
}

// ---------------- RoPE cos/sin table: [TSEQ][32] ----------------
__global__ void rope_tab(float* __restrict__ ctab, float* __restrict__ stab) {
  int idx = blockIdx.x * blockDim.x + threadIdx.x;  // 2048*32
  int t = idx >> 5, i = idx & 31;
  float inv = powf(10000.0f, -(float)i / 32.0f);
  float f = (float)t * inv;
  float sv, cv;
  sincosf(f, &sv, &cv);
  ctab[idx] = cv;
  stab[idx] = sv;
}

// ---------------- LayerNorm -> bf16 ----------------
__global__ __launch_bounds__(256) void ln_kernel(
    const float* __restrict__ x, const float* __restrict__ lw,
    const float* __restrict__ lb, unsigned short* __restrict__ xn) {
  const int row = blockIdx.x;
  const int c = threadIdx.x * 4;  // DIM/256 = 4 per thread
  const float4 v = *(const float4*)&x[(size_t)row * DIM + c];
  float s = v.x + v.y + v.z + v.w;
  float s2 = v.x * v.x + v.y * v.y + v.z * v.z + v.w * v.w;
#pragma unroll
  for (int m = 32; m; m >>= 1) {
    s += __shfl_xor(s, m);
    s2 += __shfl_xor(s2, m);
  }
  __shared__ float ps[4], ps2[4];
  if ((threadIdx.x & 63) == 0) {
    ps[threadIdx.x >> 6] = s;
    ps2[threadIdx.x >> 6] = s2;
  }
  __syncthreads();
  s = ps[0] + ps[1] + ps[2] + ps[3];
  s2 = ps2[0] + ps2[1] + ps2[2] + ps2[3];
  const float mu = s * (1.0f / DIM);
  const float rs = rsqrtf(s2 * (1.0f / DIM) - mu * mu + 1e-5f);
  const float4 wv = *(const float4*)&lw[c];
  const float4 bv = *(const float4*)&lb[c];
  ushort4 o = make_ushort4(f2bf((v.x - mu) * rs * wv.x + bv.x),
                           f2bf((v.y - mu) * rs * wv.y + bv.y),
                           f2bf((v.z - mu) * rs * wv.z + bv.z),
                           f2bf((v.w - mu) * rs * wv.w + bv.w));
  *(ushort4*)&xn[(size_t)row * DIM + c] = o;
}

// ---------------- bf16 MFMA GEMM: C[M,N] = A[M,K] * B[N,K]^T ----------------
// MODE 0: fp32 output + residual add (proj). MODE 1: bf16 output with fused
// RoPE (q,k cols) + 1/8 q-scale (qkv).
template<int MODE>
__global__ __launch_bounds__(256) void gemm_bt(
    const unsigned short* __restrict__ A, const unsigned short* __restrict__ B,
    float* __restrict__ Cf, unsigned short* __restrict__ Cb,
    const float* __restrict__ resid,
    const float* __restrict__ ctab, const float* __restrict__ stab,
    int M, int N, int K) {
  __shared__ unsigned short Al[128 * 32];
  __shared__ unsigned short Bl[128 * 32];
  const int t = threadIdx.x;
  const int lane = t & 63;
  const int wave = t >> 6;
  const int wm = wave >> 1;
  const int wn = wave & 1;
  const int bm = blockIdx.y * 128;
  const int bn = blockIdx.x * 128;

  f32x4 acc[4][4] = {};

  const int srow = t >> 2;          // 0..63: row within 64-row chunk
  const int scol = (t & 3) * 8;     // k element offset (8 bf16 = 16B)
  const unsigned short* ga = A + (size_t)(bm + srow) * K + scol;
  const unsigned short* gb = B + (size_t)(bn + srow) * K + scol;
  unsigned short* la = Al + (t & ~63) * 8;   // wave-uniform LDS base
  unsigned short* lb = Bl + (t & ~63) * 8;

  const int fr = lane & 15;
  const int fko = (lane >> 4) * 8;

  for (int k0 = 0; k0 < K; k0 += 32) {
    __syncthreads();  // previous iter's LDS reads done
    glds16(ga + k0, la);
    glds16(ga + (size_t)64 * K + k0, la + 64 * 32);
    glds16(gb + k0, lb);
    glds16(gb + (size_t)64 * K + k0, lb + 64 * 32);
    __syncthreads();  // staging complete (vmcnt(0) before barrier)
    bf16x8 af[4], bfr[4];
#pragma unroll
    for (int i = 0; i < 4; ++i)
      af[i] = *(const bf16x8*)&Al[(wm * 64 + i * 16 + fr) * 32 + fko];
#pragma unroll
    for (int j = 0; j < 4; ++j)
      bfr[j] = *(const bf16x8*)&Bl[(wn * 64 + j * 16 + fr) * 32 + fko];
#pragma unroll
    for (int i = 0; i < 4; ++i)
#pragma unroll
      for (int j = 0; j < 4; ++j)
        acc[i][j] = __builtin_amdgcn_mfma_f32_16x16x32_bf16(af[i], bfr[j], acc[i][j], 0, 0, 0);
  }

  const int cr = (lane >> 4) * 4;
  const int cc = lane & 15;
  if (MODE == 0) {
#pragma unroll
    for (int i = 0; i < 4; ++i)
#pragma unroll
      for (int j = 0; j < 4; ++j)
#pragma unroll
        for (int r = 0; r < 4; ++r) {
          int row = bm + wm * 64 + i * 16 + cr + r;
          int col = bn + wn * 64 + j * 16 + cc;
          size_t idx = (size_t)row * N + col;
          Cf[idx] = acc[i][j][r] + resid[idx];
        }
  } else {
    const int ctype = bn >> 10;  // 0=q, 1=k, 2=v
#pragma unroll
    for (int i = 0; i < 4; ++i)
#pragma unroll
      for (int r = 0; r < 4; ++r) {
        const int row = bm + wm * 64 + i * 16 + cr + r;
        const int pos = row & (TSEQ - 1);
        if (ctype == 2) {
#pragma unroll
          for (int j = 0; j < 4; ++j) {
            int col = bn + wn * 64 + j * 16 + cc;
            Cb[(size_t)row * N + col] = f2bf(acc[i][j][r]);
          }
        } else {
#pragma unroll
          for (int j = 0; j < 2; ++j) {
            int col = bn + wn * 64 + j * 16 + cc;
            float cv = ctab[pos * 32 + j * 16 + cc];
            float sv = stab[pos * 32 + j * 16 + cc];
            float lo = acc[i][j][r], hi = acc[i][j + 2][r];
            float olo = lo * cv - hi * sv;
            float ohi = hi * cv + lo * sv;
            if (ctype == 0) { olo *= 0.125f; ohi *= 0.125f; }
            Cb[(size_t)row * N + col] = f2bf(olo);
            Cb[(size_t)row * N + col + 32] = f2bf(ohi);
          }
        }
      }
  }
}

// ---------------- sliding-window attention, MFMA ----------------
// grid (T/64, B*H); block 256 (4 waves). Block handles 64 queries of one (b,h).
// Wave w: queries [qs+w*16, qs+w*16+16). Keys local kl in [0,96), global
// j = qs-32+kl; wave w uses kl in [w*16, w*16+48).
#define KST 72    // Kb row stride (u16): 144B = 36 dwords -> 2-way banks, 16B aligned
#define VST 104   // Vt row stride (u16): 208B = 52 dwords -> 2-way banks, 16B aligned
#define PST 72
__global__ __launch_bounds__(256) void attn_kernel(const unsigned short* __restrict__ qkv,
                                                   unsigned short* __restrict__ out) {
  __shared__ unsigned short Kb[96 * KST];      // 13824 B
  __shared__ unsigned short Vt[64 * VST];      // 13312 B  (V transposed: [d][key])
  __shared__ unsigned short Pl[64 * PST];      // 9216 B   (per-wave 16 rows)
  const int qtile = blockIdx.x;
  const int bh = blockIdx.y;
  const int b = bh >> 4, h = bh & 15;
  const int qs = qtile * 64;
  const int t = threadIdx.x;

  // ---- stage K rows [qs-32, qs+64) -> Kb, V same rows transposed -> Vt ----
  for (int e = t; e < 768; e += 256) {           // 96 rows x 8 segs
    int r = e >> 3, seg = e & 7;
    int j = qs - 32 + r;
    u16x8 kv = {};
    if (j >= 0)
      kv = *(const u16x8*)&qkv[((size_t)(b * TSEQ + j)) * NQKV + DIM + h * 64 + seg * 8];
    *(u16x8*)&Kb[r * KST + seg * 8] = kv;
  }
  for (int e = t; e < 768; e += 256) {
    int r = e >> 3, seg = e & 7;
    int j = qs - 32 + r;
    u16x8 vv = {};
    if (j >= 0)
      vv = *(const u16x8*)&qkv[((size_t)(b * TSEQ + j)) * NQKV + 2 * DIM + h * 64 + seg * 8];
#pragma unroll
    for (int u = 0; u < 8; ++u) Vt[(seg * 8 + u) * VST + r] = vv[u];
  }
  for (int e = t; e < 64 * PST / 8; e += 256)    // zero P (cols 48..63 stay 0)
    *(u16x8*)&Pl[e * 8] = (u16x8){};
  __syncthreads();

  const int wave = t >> 6;
  const int lane = t & 63;
  const int fr = lane & 15;
  const int fko = (lane >> 4) * 8;
  const int g = lane >> 4;
  const int cc = lane & 15;
  const int kmin = 32 - qs - wave * 16;          // global j>=0  <=>  kk >= kmin

  // ---- Q fragments straight from global (scale already folded in GEMM) ----
  const unsigned short* qrow = qkv + ((size_t)(b * TSEQ + qs + wave * 16 + fr)) * NQKV + h * 64;
  bf16x8 qf0 = *(const bf16x8*)&qrow[fko];
  bf16x8 qf1 = *(const bf16x8*)&qrow[32 + fko];

  // ---- scores: 3 key tiles x 2 k-steps ----
  f32x4 sc[3] = {};
#pragma unroll
  for (int kt = 0; kt < 3; ++kt) {
    const unsigned short* kb = &Kb[(wave * 16 + kt * 16 + fr) * KST];
    bf16x8 kf0 = *(const bf16x8*)&kb[fko];
    bf16x8 kf1 = *(const bf16x8*)&kb[32 + fko];
    sc[kt] = __builtin_amdgcn_mfma_f32_16x16x32_bf16(qf0, kf0, sc[kt], 0, 0, 0);
    sc[kt] = __builtin_amdgcn_mfma_f32_16x16x32_bf16(qf1, kf1, sc[kt], 0, 0, 0);
  }

  // ---- softmax per query row (row = g*4+reg, spread over 16 lanes x 3 kt) ----
#pragma unroll
  for (int reg = 0; reg < 4; ++reg) {
    const int r = g * 4 + reg;
    float sv[3];
    bool va[3];
    float mx = -1e30f;
#pragma unroll
    for (int kt = 0; kt < 3; ++kt) {
      int kk = kt * 16 + cc;
      bool valid = (kk >= r + 1) && (kk <= r + 32) && (kk >= kmin);
      va[kt] = valid;
      sv[kt] = valid ? sc[kt][reg] : -1e30f;
      mx = fmaxf(mx, sv[kt]);
    }
#pragma unroll
    for (int mm = 8; mm; mm >>= 1) mx = fmaxf(mx, __shfl_xor(mx, mm));
    float pe[3], sum = 0.f;
#pragma unroll
    for (int kt = 0; kt < 3; ++kt) {
      pe[kt] = va[kt] ? __expf(sv[kt] - mx) : 0.f;
      sum += pe[kt];
    }
#pragma unroll
    for (int mm = 8; mm; mm >>= 1) sum += __shfl_xor(sum, mm);
    float rinv = 1.0f / sum;
#pragma unroll
    for (int kt = 0; kt < 3; ++kt)
      Pl[(wave * 16 + r) * PST + kt * 16 + cc] = f2bf(pe[kt] * rinv);
  }

  // ---- PV: O[16 q][64 d] = P[16][64] * Vt[d][kl]^T (keys offset wave*16) ----
  const unsigned short* prow = &Pl[(wave * 16 + fr) * PST];
  bf16x8 pf0 = *(const bf16x8*)&prow[fko];
  bf16x8 pf1 = *(const bf16x8*)&prow[32 + fko];
  f32x4 o[4] = {};
#pragma unroll
  for (int nt = 0; nt < 4; ++nt) {
    const unsigned short* vrow = &Vt[(nt * 16 + fr) * VST + wave * 16];
    bf16x8 vf0 = *(const bf16x8*)&vrow[fko];
    bf16x8 vf1 = *(const bf16x8*)&vrow[32 + fko];
    o[nt] = __builtin_amdgcn_mfma_f32_16x16x32_bf16(pf0, vf0, o[nt], 0, 0, 0);
    o[nt] = __builtin_amdgcn_mfma_f32_16x16x32_bf16(pf1, vf1, o[nt], 0, 0, 0);
  }

  // ---- store O (bf16) ----
#pragma unroll
  for (int nt = 0; nt < 4; ++nt)
#pragma unroll
    for (int reg = 0; reg < 4; ++reg) {
      int qg = qs + wave * 16 + g * 4 + reg;
      out[((size_t)(b * TSEQ + qg)) * DIM + h * 64 + nt * 16 + cc] = f2bf(o[nt][reg]);
    }
}

extern "C" void kernel_launch(void* const* d_in, const int* in_sizes, int n_in,
                              void* d_out, int out_size, void* d_ws, size_t ws_size,
                              hipStream_t stream) {
  const float* x    = (const float*)d_in[0];
  const float* lw   = (const float*)d_in[1];
  const float* lbp  = (const float*)d_in[2];
  const float* wqkv = (const float*)d_in[3];
  const float* wout = (const float*)d_in[4];
  float* out = (float*)d_out;

  char* w = (char*)d_ws;
  unsigned short* xn   = (unsigned short*)(w);              //  8 MiB [4096][1024]
  unsigned short* wqb  = (unsigned short*)(w + 8388608);    //  6 MiB [3072][1024]
  unsigned short* wob  = (unsigned short*)(w + 14680064);   //  2 MiB [1024][1024]
  unsigned short* atb  = (unsigned short*)(w + 16777216);   //  8 MiB [4096][1024]
  float* ctab = (float*)(w + 25165824);                     // 256 KiB
  float* stab = (float*)(w + 25427968);                     // 256 KiB
  unsigned short* qkvb = (unsigned short*)(w + 25690112);   // 24 MiB [4096][3072]

  cvt_bf16<<<3072, 256, 0, stream>>>(wqkv, wqb, 786432);
  cvt_bf16<<<1024, 256, 0, stream>>>(wout, wob, 262144);
  rope_tab<<<256, 256, 0, stream>>>(ctab, stab);
  ln_kernel<<<ROWS, 256, 0, stream>>>(x, lw, lbp, xn);
  gemm_bt<1><<<dim3(24, 32), 256, 0, stream>>>(xn, wqb, nullptr, qkvb, nullptr,
                                               ctab, stab, ROWS, NQKV, DIM);
  attn_kernel<<<dim3(32, 32), 256, 0, stream>>>(qkvb, atb);
  gemm_bt<0><<<dim3(8, 32), 256, 0, stream>>>(atb, wob, out, nullptr, x,
                                              nullptr, nullptr, ROWS, DIM, DIM);
}

// Round 4
// 100.559 us; speedup vs baseline: 1.7228x; 1.0053x over previous
//
#include <hip/hip_runtime.h>
#include <hip/hip_bf16.h>
#include <math.h>

#define DIM 1024
#define HEADS 16
#define DH 64
#define WINDOW 32
#define TSEQ 2048
#define BB 2
#define ROWS (BB * TSEQ)      // 4096
#define NQKV (3 * DIM)        // 3072

typedef __bf16 bf16x8 __attribute__((ext_vector_type(8)));
typedef unsigned short u16x8 __attribute__((ext_vector_type(8)));
typedef float f32x4 __attribute__((ext_vector_type(4)));

__device__ __forceinline__ unsigned short f2bf(float f) {
  unsigned int u = __float_as_uint(f);
  u += 0x7fffu + ((u >> 16) & 1u);   // round-to-nearest-even
  return (unsigned short)(u >> 16);
}

__device__ __forceinline__ void glds16(const void* g, void* l) {
  __builtin_amdgcn_global_load_lds((const __attribute__((address_space(1))) void*)g,
                                   (__attribute__((address_space(3))) void*)l,
                                   16, 0, 0);
}

// ---------------- weight fp32 -> bf16 conversion ----------------
__global__ void cvt_bf16(const float* __restrict__ in, unsigned short* __restrict__ out, int n4) {
  int i = blockIdx.x * blockDim.x + threadIdx.x;
  if (i < n4) {
    float4 v = *(const float4*)&in[(size_t)i * 4];
    ushort4 o = make_ushort4(f2bf(v.x), f2bf(v.y), f2bf(v.z), f2bf(v.w));
    *(ushort4*)&out[(size_t)i * 4] = o;
  }
}

// ---------------- RoPE cos/sin table: [TSEQ][32] ----------------
__global__ void rope_tab(float* __restrict__ ctab, float* __restrict__ stab) {
  int idx = blockIdx.x * blockDim.x + threadIdx.x;  // 2048*32
  int t = idx >> 5, i = idx & 31;
  float inv = powf(10000.0f, -(float)i / 32.0f);
  float f = (float)t * inv;
  float sv, cv;
  sincosf(f, &sv, &cv);
  ctab[idx] = cv;
  stab[idx] = sv;
}

// ---------------- LayerNorm -> bf16 ----------------
__global__ __launch_bounds__(256) void ln_kernel(
    const float* __restrict__ x, const float* __restrict__ lw,
    const float* __restrict__ lb, unsigned short* __restrict__ xn) {
  const int row = blockIdx.x;
  const int c = threadIdx.x * 4;  // DIM/256 = 4 per thread
  const float4 v = *(const float4*)&x[(size_t)row * DIM + c];
  float s = v.x + v.y + v.z + v.w;
  float s2 = v.x * v.x + v.y * v.y + v.z * v.z + v.w * v.w;
#pragma unroll
  for (int m = 32; m; m >>= 1) {
    s += __shfl_xor(s, m);
    s2 += __shfl_xor(s2, m);
  }
  __shared__ float ps[4], ps2[4];
  if ((threadIdx.x & 63) == 0) {
    ps[threadIdx.x >> 6] = s;
    ps2[threadIdx.x >> 6] = s2;
  }
  __syncthreads();
  s = ps[0] + ps[1] + ps[2] + ps[3];
  s2 = ps2[0] + ps2[1] + ps2[2] + ps2[3];
  const float mu = s * (1.0f / DIM);
  const float rs = rsqrtf(s2 * (1.0f / DIM) - mu * mu + 1e-5f);
  const float4 wv = *(const float4*)&lw[c];
  const float4 bv = *(const float4*)&lb[c];
  ushort4 o = make_ushort4(f2bf((v.x - mu) * rs * wv.x + bv.x),
                           f2bf((v.y - mu) * rs * wv.y + bv.y),
                           f2bf((v.z - mu) * rs * wv.z + bv.z),
                           f2bf((v.w - mu) * rs * wv.w + bv.w));
  *(ushort4*)&xn[(size_t)row * DIM + c] = o;
}

// ---------------- bf16 MFMA GEMM: C[M,N] = A[M,K] * B[N,K]^T ----------------
// MODE 0: fp32 output + residual add (proj). MODE 1: bf16 output with fused
// RoPE (q,k cols) + 1/8 q-scale (qkv).
template<int MODE>
__global__ __launch_bounds__(256) void gemm_bt(
    const unsigned short* __restrict__ A, const unsigned short* __restrict__ B,
    float* __restrict__ Cf, unsigned short* __restrict__ Cb,
    const float* __restrict__ resid,
    const float* __restrict__ ctab, const float* __restrict__ stab,
    int M, int N, int K) {
  __shared__ unsigned short Al[128 * 32];
  __shared__ unsigned short Bl[128 * 32];
  const int t = threadIdx.x;
  const int lane = t & 63;
  const int wave = t >> 6;
  const int wm = wave >> 1;
  const int wn = wave & 1;
  const int bm = blockIdx.y * 128;
  const int bn = blockIdx.x * 128;

  f32x4 acc[4][4] = {};

  const int srow = t >> 2;          // 0..63: row within 64-row chunk
  const int scol = (t & 3) * 8;     // k element offset (8 bf16 = 16B)
  const unsigned short* ga = A + (size_t)(bm + srow) * K + scol;
  const unsigned short* gb = B + (size_t)(bn + srow) * K + scol;
  unsigned short* la = Al + (t & ~63) * 8;   // wave-uniform LDS base
  unsigned short* lb = Bl + (t & ~63) * 8;

  const int fr = lane & 15;
  const int fko = (lane >> 4) * 8;

  for (int k0 = 0; k0 < K; k0 += 32) {
    __syncthreads();  // previous iter's LDS reads done
    glds16(ga + k0, la);
    glds16(ga + (size_t)64 * K + k0, la + 64 * 32);
    glds16(gb + k0, lb);
    glds16(gb + (size_t)64 * K + k0, lb + 64 * 32);
    __syncthreads();  // staging complete (vmcnt(0) before barrier)
    bf16x8 af[4], bfr[4];
#pragma unroll
    for (int i = 0; i < 4; ++i)
      af[i] = *(const bf16x8*)&Al[(wm * 64 + i * 16 + fr) * 32 + fko];
#pragma unroll
    for (int j = 0; j < 4; ++j)
      bfr[j] = *(const bf16x8*)&Bl[(wn * 64 + j * 16 + fr) * 32 + fko];
#pragma unroll
    for (int i = 0; i < 4; ++i)
#pragma unroll
      for (int j = 0; j < 4; ++j)
        acc[i][j] = __builtin_amdgcn_mfma_f32_16x16x32_bf16(af[i], bfr[j], acc[i][j], 0, 0, 0);
  }

  const int cr = (lane >> 4) * 4;
  const int cc = lane & 15;
  if (MODE == 0) {
#pragma unroll
    for (int i = 0; i < 4; ++i)
#pragma unroll
      for (int j = 0; j < 4; ++j)
#pragma unroll
        for (int r = 0; r < 4; ++r) {
          int row = bm + wm * 64 + i * 16 + cr + r;
          int col = bn + wn * 64 + j * 16 + cc;
          size_t idx = (size_t)row * N + col;
          Cf[idx] = acc[i][j][r] + resid[idx];
        }
  } else {
    const int ctype = bn >> 10;  // 0=q, 1=k, 2=v
#pragma unroll
    for (int i = 0; i < 4; ++i)
#pragma unroll
      for (int r = 0; r < 4; ++r) {
        const int row = bm + wm * 64 + i * 16 + cr + r;
        const int pos = row & (TSEQ - 1);
        if (ctype == 2) {
#pragma unroll
          for (int j = 0; j < 4; ++j) {
            int col = bn + wn * 64 + j * 16 + cc;
            Cb[(size_t)row * N + col] = f2bf(acc[i][j][r]);
          }
        } else {
#pragma unroll
          for (int j = 0; j < 2; ++j) {
            int col = bn + wn * 64 + j * 16 + cc;
            float cv = ctab[pos * 32 + j * 16 + cc];
            float sv = stab[pos * 32 + j * 16 + cc];
            float lo = acc[i][j][r], hi = acc[i][j + 2][r];
            float olo = lo * cv - hi * sv;
            float ohi = hi * cv + lo * sv;
            if (ctype == 0) { olo *= 0.125f; ohi *= 0.125f; }
            Cb[(size_t)row * N + col] = f2bf(olo);
            Cb[(size_t)row * N + col + 32] = f2bf(ohi);
          }
        }
      }
  }
}

// ---------------- sliding-window attention, MFMA ----------------
// grid (T/64, B*H); block 256 (4 waves). Block handles 64 queries of one (b,h).
// Wave w: queries [qs+w*16, qs+w*16+16). Keys local kl in [0,96), global
// j = qs-32+kl; wave w uses kl in [w*16, w*16+48).
#define KST 72    // Kb row stride (u16): 144B = 36 dwords -> 2-way banks, 16B aligned
#define VST 104   // Vt row stride (u16): 208B = 52 dwords -> 2-way banks, 16B aligned
#define PST 72
__global__ __launch_bounds__(256) void attn_kernel(const unsigned short* __restrict__ qkv,
                                                   unsigned short* __restrict__ out) {
  __shared__ unsigned short Kb[96 * KST];      // 13824 B
  __shared__ unsigned short Vt[64 * VST];      // 13312 B  (V transposed: [d][key])
  __shared__ unsigned short Pl[64 * PST];      // 9216 B   (per-wave 16 rows)
  const int qtile = blockIdx.x;
  const int bh = blockIdx.y;
  const int b = bh >> 4, h = bh & 15;
  const int qs = qtile * 64;
  const int t = threadIdx.x;

  // ---- stage K rows [qs-32, qs+64) -> Kb, V same rows transposed -> Vt ----
  for (int e = t; e < 768; e += 256) {           // 96 rows x 8 segs
    int r = e >> 3, seg = e & 7;
    int j = qs - 32 + r;
    u16x8 kv = {};
    if (j >= 0)
      kv = *(const u16x8*)&qkv[((size_t)(b * TSEQ + j)) * NQKV + DIM + h * 64 + seg * 8];
    *(u16x8*)&Kb[r * KST + seg * 8] = kv;
  }
  for (int e = t; e < 768; e += 256) {
    int r = e >> 3, seg = e & 7;
    int j = qs - 32 + r;
    u16x8 vv = {};
    if (j >= 0)
      vv = *(const u16x8*)&qkv[((size_t)(b * TSEQ + j)) * NQKV + 2 * DIM + h * 64 + seg * 8];
#pragma unroll
    for (int u = 0; u < 8; ++u) Vt[(seg * 8 + u) * VST + r] = vv[u];
  }
  for (int e = t; e < 64 * PST / 8; e += 256)    // zero P (cols 48..63 stay 0)
    *(u16x8*)&Pl[e * 8] = (u16x8){};
  __syncthreads();

  const int wave = t >> 6;
  const int lane = t & 63;
  const int fr = lane & 15;
  const int fko = (lane >> 4) * 8;
  const int g = lane >> 4;
  const int cc = lane & 15;
  const int kmin = 32 - qs - wave * 16;          // global j>=0  <=>  kk >= kmin

  // ---- Q fragments straight from global (scale already folded in GEMM) ----
  const unsigned short* qrow = qkv + ((size_t)(b * TSEQ + qs + wave * 16 + fr)) * NQKV + h * 64;
  bf16x8 qf0 = *(const bf16x8*)&qrow[fko];
  bf16x8 qf1 = *(const bf16x8*)&qrow[32 + fko];

  // ---- scores: 3 key tiles x 2 k-steps ----
  f32x4 sc[3] = {};
#pragma unroll
  for (int kt = 0; kt < 3; ++kt) {
    const unsigned short* kb = &Kb[(wave * 16 + kt * 16 + fr) * KST];
    bf16x8 kf0 = *(const bf16x8*)&kb[fko];
    bf16x8 kf1 = *(const bf16x8*)&kb[32 + fko];
    sc[kt] = __builtin_amdgcn_mfma_f32_16x16x32_bf16(qf0, kf0, sc[kt], 0, 0, 0);
    sc[kt] = __builtin_amdgcn_mfma_f32_16x16x32_bf16(qf1, kf1, sc[kt], 0, 0, 0);
  }

  // ---- softmax per query row (row = g*4+reg, spread over 16 lanes x 3 kt) ----
#pragma unroll
  for (int reg = 0; reg < 4; ++reg) {
    const int r = g * 4 + reg;
    float sv[3];
    bool va[3];
    float mx = -1e30f;
#pragma unroll
    for (int kt = 0; kt < 3; ++kt) {
      int kk = kt * 16 + cc;
      bool valid = (kk >= r + 1) && (kk <= r + 32) && (kk >= kmin);
      va[kt] = valid;
      sv[kt] = valid ? sc[kt][reg] : -1e30f;
      mx = fmaxf(mx, sv[kt]);
    }
#pragma unroll
    for (int mm = 8; mm; mm >>= 1) mx = fmaxf(mx, __shfl_xor(mx, mm));
    float pe[3], sum = 0.f;
#pragma unroll
    for (int kt = 0; kt < 3; ++kt) {
      pe[kt] = va[kt] ? __expf(sv[kt] - mx) : 0.f;
      sum += pe[kt];
    }
#pragma unroll
    for (int mm = 8; mm; mm >>= 1) sum += __shfl_xor(sum, mm);
    float rinv = 1.0f / sum;
#pragma unroll
    for (int kt = 0; kt < 3; ++kt)
      Pl[(wave * 16 + r) * PST + kt * 16 + cc] = f2bf(pe[kt] * rinv);
  }

  // ---- PV: O[16 q][64 d] = P[16][64] * Vt[d][kl]^T (keys offset wave*16) ----
  const unsigned short* prow = &Pl[(wave * 16 + fr) * PST];
  bf16x8 pf0 = *(const bf16x8*)&prow[fko];
  bf16x8 pf1 = *(const bf16x8*)&prow[32 + fko];
  f32x4 o[4] = {};
#pragma unroll
  for (int nt = 0; nt < 4; ++nt) {
    const unsigned short* vrow = &Vt[(nt * 16 + fr) * VST + wave * 16];
    bf16x8 vf0 = *(const bf16x8*)&vrow[fko];
    bf16x8 vf1 = *(const bf16x8*)&vrow[32 + fko];
    o[nt] = __builtin_amdgcn_mfma_f32_16x16x32_bf16(pf0, vf0, o[nt], 0, 0, 0);
    o[nt] = __builtin_amdgcn_mfma_f32_16x16x32_bf16(pf1, vf1, o[nt], 0, 0, 0);
  }

  // ---- store O (bf16) ----
#pragma unroll
  for (int nt = 0; nt < 4; ++nt)
#pragma unroll
    for (int reg = 0; reg < 4; ++reg) {
      int qg = qs + wave * 16 + g * 4 + reg;
      out[((size_t)(b * TSEQ + qg)) * DIM + h * 64 + nt * 16 + cc] = f2bf(o[nt][reg]);
    }
}

extern "C" void kernel_launch(void* const* d_in, const int* in_sizes, int n_in,
                              void* d_out, int out_size, void* d_ws, size_t ws_size,
                              hipStream_t stream) {
  const float* x    = (const float*)d_in[0];
  const float* lw   = (const float*)d_in[1];
  const float* lbp  = (const float*)d_in[2];
  const float* wqkv = (const float*)d_in[3];
  const float* wout = (const float*)d_in[4];
  float* out = (float*)d_out;

  char* w = (char*)d_ws;
  unsigned short* xn   = (unsigned short*)(w);              //  8 MiB [4096][1024]
  unsigned short* wqb  = (unsigned short*)(w + 8388608);    //  6 MiB [3072][1024]
  unsigned short* wob  = (unsigned short*)(w + 14680064);   //  2 MiB [1024][1024]
  unsigned short* atb  = (unsigned short*)(w + 16777216);   //  8 MiB [4096][1024]
  float* ctab = (float*)(w + 25165824);                     // 256 KiB
  float* stab = (float*)(w + 25427968);                     // 256 KiB
  unsigned short* qkvb = (unsigned short*)(w + 25690112);   // 24 MiB [4096][3072]

  cvt_bf16<<<3072, 256, 0, stream>>>(wqkv, wqb, 786432);
  cvt_bf16<<<1024, 256, 0, stream>>>(wout, wob, 262144);
  rope_tab<<<256, 256, 0, stream>>>(ctab, stab);
  ln_kernel<<<ROWS, 256, 0, stream>>>(x, lw, lbp, xn);
  gemm_bt<1><<<dim3(24, 32), 256, 0, stream>>>(xn, wqb, nullptr, qkvb, nullptr,
                                               ctab, stab, ROWS, NQKV, DIM);
  attn_kernel<<<dim3(32, 32), 256, 0, stream>>>(qkvb, atb);
  gemm_bt<0><<<dim3(8, 32), 256, 0, stream>>>(atb, wob, out, nullptr, x,
                                              nullptr, nullptr, ROWS, DIM, DIM);
}